// Round 3
// baseline (594.361 us; speedup 1.0000x reference)
//
#include <hip/hip_runtime.h>
#include <hip/hip_bf16.h>
#include <math.h>

// AdaptGNN: B=8, N=2048, D=H=128, 3 layers.
// Round 3: agg with 16-wave blocks (4 waves/SIMD) + ew register prefetch +
// single-barrier double-buffered S' LDS; linear via bf16 MFMA; h carried bf16.

typedef __attribute__((ext_vector_type(8))) short bf16x8;
typedef __attribute__((ext_vector_type(4))) short bf16x4;
typedef __attribute__((ext_vector_type(4))) float f32x4;

static constexpr int kB = 8, kN = 2048, kH = 128;
static constexpr int kSstr = 136; // S' LDS stride (ushorts): 272 B rows, 16B-aligned

static __device__ __forceinline__ ushort bf16bits(float f) {
    __hip_bfloat16 hb = __float2bfloat16(f);
    return *reinterpret_cast<ushort*>(&hb);
}

// ---------------- converts ----------------
__global__ __launch_bounds__(256) void cvt_bf16_kernel(
    const float* __restrict__ src, ushort* __restrict__ dst, int n4)
{
    int i = blockIdx.x * 256 + threadIdx.x;
    if (i >= n4) return;
    float4 v = ((const float4*)src)[i];
    bf16x4 o;
    o[0] = (short)bf16bits(v.x); o[1] = (short)bf16bits(v.y);
    o[2] = (short)bf16bits(v.z); o[3] = (short)bf16bits(v.w);
    ((bf16x4*)dst)[i] = o;
}

// WT16[c][d] = bf16(W[d][c])
__global__ __launch_bounds__(256) void cvt_wT_kernel(
    const float* __restrict__ W, ushort* __restrict__ WT)
{
    int i = blockIdx.x * 256 + threadIdx.x;  // 0..16383
    int d = i >> 7, c = i & 127;
    WT[c * kH + d] = bf16bits(W[d * kH + c]);
}

// ---------------- linear (bf16 MFMA) + row-norm ----------------
// t16 = bf16(h16@W + b), invn = 1/max(||row||,eps). 64 rows/block, 4 waves (2r x 2c).
__global__ __launch_bounds__(256) void linear_mfma_kernel(
    const ushort* __restrict__ h16, const ushort* __restrict__ WT,
    const float* __restrict__ bias, ushort* __restrict__ t16,
    float* __restrict__ invn)
{
    __shared__ float ssb[64][2];

    const int tid = threadIdx.x, lane = tid & 63, wid = tid >> 6;
    const int wr = wid >> 1, wc = wid & 1, quad = lane >> 4, l16 = lane & 15;
    const int rowbase = blockIdx.x * 64;

    f32x4 acc[2][4];
#pragma unroll
    for (int i = 0; i < 2; ++i)
#pragma unroll
        for (int ct = 0; ct < 4; ++ct) acc[i][ct] = (f32x4){0.f, 0.f, 0.f, 0.f};

#pragma unroll
    for (int k = 0; k < 4; ++k) {
        bf16x8 Af[2], Bf[4];
#pragma unroll
        for (int i = 0; i < 2; ++i)
            Af[i] = *(const bf16x8*)&h16[(size_t)(rowbase + wr * 32 + i * 16 + l16) * kH + k * 32 + quad * 8];
#pragma unroll
        for (int ct = 0; ct < 4; ++ct)
            Bf[ct] = *(const bf16x8*)&WT[(size_t)(wc * 64 + ct * 16 + l16) * kH + k * 32 + quad * 8];
#pragma unroll
        for (int i = 0; i < 2; ++i)
#pragma unroll
            for (int ct = 0; ct < 4; ++ct)
                acc[i][ct] = __builtin_amdgcn_mfma_f32_16x16x32_bf16(Af[i], Bf[ct], acc[i][ct], 0, 0, 0);
    }

    float bsr[4];
#pragma unroll
    for (int ct = 0; ct < 4; ++ct) bsr[ct] = bias[wc * 64 + ct * 16 + l16];

    f32x4 ss[2] = {(f32x4){0,0,0,0}, (f32x4){0,0,0,0}};
#pragma unroll
    for (int i = 0; i < 2; ++i)
#pragma unroll
        for (int ct = 0; ct < 4; ++ct)
#pragma unroll
            for (int r = 0; r < 4; ++r) {
                float v = acc[i][ct][r] + bsr[ct];
                acc[i][ct][r] = v;
                ss[i][r] += v * v;
            }
#pragma unroll
    for (int step = 1; step < 16; step <<= 1)
#pragma unroll
        for (int i = 0; i < 2; ++i)
#pragma unroll
            for (int r = 0; r < 4; ++r) ss[i][r] += __shfl_xor(ss[i][r], step);

    if (l16 == 0)
#pragma unroll
        for (int i = 0; i < 2; ++i)
#pragma unroll
            for (int r = 0; r < 4; ++r)
                ssb[wr * 32 + i * 16 + quad * 4 + r][wc] = ss[i][r];
    __syncthreads();
    if (tid < 64) {
        float s2 = ssb[tid][0] + ssb[tid][1];
        invn[rowbase + tid] = 1.f / fmaxf(sqrtf(s2), 1e-12f);
    }

#pragma unroll
    for (int i = 0; i < 2; ++i)
#pragma unroll
        for (int ct = 0; ct < 4; ++ct)
#pragma unroll
            for (int r = 0; r < 4; ++r) {
                const int row = rowbase + wr * 32 + i * 16 + quad * 4 + r;
                const int c = wc * 64 + ct * 16 + l16;
                t16[(size_t)row * kH + c] = bf16bits(acc[i][ct][r]);
            }
}

// ---------------- transpose: t16[b][q][d] -> tT[b][d][q] ----------------
__global__ __launch_bounds__(256) void transpose_kernel(
    const ushort* __restrict__ t, ushort* __restrict__ tT)
{
    __shared__ ushort tile[64][72];
    const int b = blockIdx.z;
    const int qb = blockIdx.x * 64;
    const int db = blockIdx.y * 64;
    const int tid = threadIdx.x;
    const int r  = tid >> 3;
    const int cg = (tid & 7) * 8;
#pragma unroll
    for (int it = 0; it < 2; ++it) {
        const int row = r + 32 * it;
        bf16x8 v = *(const bf16x8*)&t[(size_t)(b * kN + qb + row) * kH + db + cg];
        *(bf16x8*)&tile[row][cg] = v;
    }
    __syncthreads();
#pragma unroll
    for (int it = 0; it < 2; ++it) {
        const int d = r + 32 * it;
        bf16x8 o;
#pragma unroll
        for (int j = 0; j < 8; ++j) o[j] = (short)tile[cg + j][d];
        *(bf16x8*)&tT[(size_t)(b * kH + db + d) * kN + qb + cg] = o;
    }
}

// ---------------- fused MFMA aggregation ----------------
// 1024 threads = 16 waves, wave grid 4(p) x 4(q/c). 64 P-rows per block.
// ew register-prefetched one q-tile ahead; S' double-buffered (1 barrier/tile).
__global__ __launch_bounds__(1024) void agg_kernel(
    const ushort* __restrict__ t, const ushort* __restrict__ tT,
    const float* __restrict__ invn, const float* __restrict__ ew,
    ushort* __restrict__ hout, float* __restrict__ fout, int last)
{
    __shared__ ushort Sp[2][64 * kSstr];  // 34.8 KB
    __shared__ float invPs[64];

    const int b = blockIdx.y, pbase = blockIdx.x * 64;
    const int tid = threadIdx.x, lane = tid & 63, wid = tid >> 6;
    const int wp = wid >> 2, wq = wid & 3, quad = lane >> 4, l16 = lane & 15;

    const ushort* tb  = t  + (size_t)b * kN * kH;
    const ushort* tTb = tT + (size_t)b * kH * kN;
    const float* ewb  = ew + (size_t)b * kN * kN;
    const float* invb = invn + b * kN;

    if (tid < 64) invPs[tid] = invb[pbase + tid];

    // A-frags for this wave's 16 P-rows (reused across all 16 q-tiles)
    bf16x8 Af[4];
#pragma unroll
    for (int k = 0; k < 4; ++k)
        Af[k] = *(const bf16x8*)&tb[(size_t)(pbase + wp * 16 + l16) * kH + k * 32 + quad * 8];

    __syncthreads();
    float invPr[4];
#pragma unroll
    for (int r = 0; r < 4; ++r) invPr[r] = invPs[wp * 16 + quad * 4 + r];

    const int prow = pbase + wp * 16 + quad * 4;

    float ewc[2][4], ewn[2][4], invQc[2], invQn[2];
#pragma unroll
    for (int jt = 0; jt < 2; ++jt) {
        const int qc = wq * 32 + jt * 16 + l16;
        invQc[jt] = invb[qc];
#pragma unroll
        for (int r = 0; r < 4; ++r) ewc[jt][r] = ewb[(size_t)(prow + r) * kN + qc];
    }

    f32x4 oacc[2] = {(f32x4){0,0,0,0}, (f32x4){0,0,0,0}};

    for (int qt = 0; qt < kN / 128; ++qt) {
        const int qbase = qt * 128;

        if (qt < kN / 128 - 1) {
            const int qb2 = qbase + 128;
#pragma unroll
            for (int jt = 0; jt < 2; ++jt) {
                const int qc = qb2 + wq * 32 + jt * 16 + l16;
                invQn[jt] = invb[qc];
#pragma unroll
                for (int r = 0; r < 4; ++r) ewn[jt][r] = ewb[(size_t)(prow + r) * kN + qc];
            }
        }

        // ---- S-phase ----
        f32x4 dacc[2] = {(f32x4){0,0,0,0}, (f32x4){0,0,0,0}};
#pragma unroll
        for (int k = 0; k < 4; ++k) {
            bf16x8 Bf0 = *(const bf16x8*)&tb[(size_t)(qbase + wq * 32 + l16) * kH + k * 32 + quad * 8];
            bf16x8 Bf1 = *(const bf16x8*)&tb[(size_t)(qbase + wq * 32 + 16 + l16) * kH + k * 32 + quad * 8];
            dacc[0] = __builtin_amdgcn_mfma_f32_16x16x32_bf16(Af[k], Bf0, dacc[0], 0, 0, 0);
            dacc[1] = __builtin_amdgcn_mfma_f32_16x16x32_bf16(Af[k], Bf1, dacc[1], 0, 0, 0);
        }

        // ---- epilogue: S' = dacc * ew * invQ (invP deferred to O store) ----
        ushort* Sq = Sp[qt & 1];
#pragma unroll
        for (int jt = 0; jt < 2; ++jt)
#pragma unroll
            for (int r = 0; r < 4; ++r) {
                float s = dacc[jt][r] * ewc[jt][r] * invQc[jt];
                Sq[(wp * 16 + quad * 4 + r) * kSstr + wq * 32 + jt * 16 + l16] = bf16bits(s);
            }
        __syncthreads();

        // ---- O-phase: oacc += S'[p, qbase:qbase+128] @ t[qbase:qbase+128, c] ----
#pragma unroll
        for (int k = 0; k < 4; ++k) {
            bf16x8 Sa = *(const bf16x8*)&Sq[(wp * 16 + l16) * kSstr + k * 32 + quad * 8];
#pragma unroll
            for (int ct = 0; ct < 2; ++ct) {
                bf16x8 Bb = *(const bf16x8*)&tTb[(size_t)(wq * 32 + ct * 16 + l16) * kN + qbase + k * 32 + quad * 8];
                oacc[ct] = __builtin_amdgcn_mfma_f32_16x16x32_bf16(Sa, Bb, oacc[ct], 0, 0, 0);
            }
        }

#pragma unroll
        for (int jt = 0; jt < 2; ++jt) {
            invQc[jt] = invQn[jt];
#pragma unroll
            for (int r = 0; r < 4; ++r) ewc[jt][r] = ewn[jt][r];
        }
    }

    // ---- store: O * invP (+relu -> bf16 h, or fp32 out) ----
#pragma unroll
    for (int ct = 0; ct < 2; ++ct)
#pragma unroll
        for (int r = 0; r < 4; ++r) {
            const int p = pbase + wp * 16 + quad * 4 + r;
            const int c = wq * 32 + ct * 16 + l16;
            float v = oacc[ct][r] * invPr[r];
            if (!last) {
                hout[(size_t)b * kN * kH + (size_t)p * kH + c] = bf16bits(fmaxf(v, 0.f));
            } else {
                fout[(size_t)b * kN * kH + (size_t)p * kH + c] = v;
            }
        }
}

extern "C" void kernel_launch(void* const* d_in, const int* in_sizes, int n_in,
                              void* d_out, int out_size, void* d_ws, size_t ws_size,
                              hipStream_t stream) {
    const float* x  = (const float*)d_in[0];
    const float* ew = (const float*)d_in[1];
    const float* W[3]    = {(const float*)d_in[2], (const float*)d_in[4], (const float*)d_in[6]};
    const float* bias[3] = {(const float*)d_in[3], (const float*)d_in[5], (const float*)d_in[7]};

    const size_t nBNH = (size_t)kB * kN * kH;  // 2M elements
    // ws layout (~12.3 MB): h16/x16 | t16 | tT16 | invn | WT16 x3
    ushort* h16  = (ushort*)d_ws;               // [B,N,H] bf16 (x16 for layer 0; reused as h)
    ushort* t16  = h16 + nBNH;                  // [B,N,H] bf16 post-linear
    ushort* tT16 = t16 + nBNH;                  // [B,H,N] bf16 transposed
    float*  invn = (float*)(tT16 + nBNH);       // [B,N]
    ushort* WT   = (ushort*)(invn + (size_t)kB * kN);  // 3 x [H,D] bf16
    float*  out  = (float*)d_out;

    cvt_bf16_kernel<<<(int)(nBNH / 4 + 255) / 256, 256, 0, stream>>>(x, h16, (int)(nBNH / 4));
    for (int l = 0; l < 3; ++l)
        cvt_wT_kernel<<<64, 256, 0, stream>>>(W[l], WT + (size_t)l * kH * kH);

    for (int layer = 0; layer < 3; ++layer) {
        linear_mfma_kernel<<<kB * kN / 64, 256, 0, stream>>>(
            h16, WT + (size_t)layer * kH * kH, bias[layer], t16, invn);
        transpose_kernel<<<dim3(kN / 64, kH / 64, kB), 256, 0, stream>>>(t16, tT16);
        agg_kernel<<<dim3(kN / 64, kB), 1024, 0, stream>>>(
            t16, tT16, invn, ew, h16, out, layer == 2 ? 1 : 0);
    }
}

// Round 4
// 341.181 us; speedup vs baseline: 1.7421x; 1.7421x over previous
//
#include <hip/hip_runtime.h>
#include <hip/hip_bf16.h>
#include <math.h>

// AdaptGNN: B=8, N=2048, D=H=128, 3 layers.
// R4: agg reads all MFMA fragments from LDS (staged with coalesced global
// loads) to kill the TA bottleneck (64-lines-per-instr fragment loads).
// Linear kernel fused with the transpose (tT written via LDS round-trip).

typedef __attribute__((ext_vector_type(8))) short bf16x8;
typedef __attribute__((ext_vector_type(4))) short bf16x4;
typedef __attribute__((ext_vector_type(4))) float f32x4;

static constexpr int kB = 8, kN = 2048, kH = 128;

static __device__ __forceinline__ ushort bf16bits(float f) {
    __hip_bfloat16 hb = __float2bfloat16(f);
    return *reinterpret_cast<ushort*>(&hb);
}

// ---------------- x -> bf16 ----------------
__global__ __launch_bounds__(256) void cvt_bf16_kernel(
    const float* __restrict__ src, ushort* __restrict__ dst, int n4)
{
    int i = blockIdx.x * 256 + threadIdx.x;
    if (i >= n4) return;
    float4 v = ((const float4*)src)[i];
    bf16x4 o;
    o[0] = (short)bf16bits(v.x); o[1] = (short)bf16bits(v.y);
    o[2] = (short)bf16bits(v.z); o[3] = (short)bf16bits(v.w);
    ((bf16x4*)dst)[i] = o;
}

// WT[l][c][d] = bf16(W_l[d][c]) — all 3 layers in one launch
__global__ __launch_bounds__(256) void cvt_wT_kernel(
    const float* __restrict__ W0, const float* __restrict__ W1,
    const float* __restrict__ W2, ushort* __restrict__ WT)
{
    const float* W = blockIdx.y == 0 ? W0 : (blockIdx.y == 1 ? W1 : W2);
    int i = blockIdx.x * 256 + threadIdx.x;  // 0..16383
    int d = i >> 7, c = i & 127;
    WT[(size_t)blockIdx.y * kH * kH + c * kH + d] = bf16bits(W[d * kH + c]);
}

// ---------------- linear (bf16 MFMA) + row-norm + transpose-out ----------------
// 64 rows/block (one batch slice), 256 thr = 4 waves (2r x 2c).
// Outputs: t16[b][q][d], tT16[b][d][q], invn[b][q].
__global__ __launch_bounds__(256) void linear_tr_kernel(
    const ushort* __restrict__ h16, const ushort* __restrict__ WT,
    const float* __restrict__ bias, ushort* __restrict__ t16,
    ushort* __restrict__ tT16, float* __restrict__ invn)
{
    __shared__ float ssb[64][2];
    __shared__ ushort tr[128 * 72];  // [c][p_local], stride 72 (144B, 4-bank rotate)

    const int tid = threadIdx.x, lane = tid & 63, wid = tid >> 6;
    const int wr = wid >> 1, wc = wid & 1, quad = lane >> 4, l16 = lane & 15;
    const int rowbase = blockIdx.x * 64;           // global BN row
    const int b = rowbase / kN, q0 = rowbase % kN; // batch / in-batch row

    f32x4 acc[2][4];
#pragma unroll
    for (int i = 0; i < 2; ++i)
#pragma unroll
        for (int ct = 0; ct < 4; ++ct) acc[i][ct] = (f32x4){0.f, 0.f, 0.f, 0.f};

#pragma unroll
    for (int k = 0; k < 4; ++k) {
        bf16x8 Af[2], Bf[4];
#pragma unroll
        for (int i = 0; i < 2; ++i)
            Af[i] = *(const bf16x8*)&h16[(size_t)(rowbase + wr * 32 + i * 16 + l16) * kH + k * 32 + quad * 8];
#pragma unroll
        for (int ct = 0; ct < 4; ++ct)
            Bf[ct] = *(const bf16x8*)&WT[(size_t)(wc * 64 + ct * 16 + l16) * kH + k * 32 + quad * 8];
#pragma unroll
        for (int i = 0; i < 2; ++i)
#pragma unroll
            for (int ct = 0; ct < 4; ++ct)
                acc[i][ct] = __builtin_amdgcn_mfma_f32_16x16x32_bf16(Af[i], Bf[ct], acc[i][ct], 0, 0, 0);
    }

    float bsr[4];
#pragma unroll
    for (int ct = 0; ct < 4; ++ct) bsr[ct] = bias[wc * 64 + ct * 16 + l16];

    f32x4 ss[2] = {(f32x4){0,0,0,0}, (f32x4){0,0,0,0}};
#pragma unroll
    for (int i = 0; i < 2; ++i)
#pragma unroll
        for (int ct = 0; ct < 4; ++ct)
#pragma unroll
            for (int r = 0; r < 4; ++r) {
                float v = acc[i][ct][r] + bsr[ct];
                acc[i][ct][r] = v;
                ss[i][r] += v * v;
            }
#pragma unroll
    for (int step = 1; step < 16; step <<= 1)
#pragma unroll
        for (int i = 0; i < 2; ++i)
#pragma unroll
            for (int r = 0; r < 4; ++r) ss[i][r] += __shfl_xor(ss[i][r], step);

    if (l16 == 0)
#pragma unroll
        for (int i = 0; i < 2; ++i)
#pragma unroll
            for (int r = 0; r < 4; ++r)
                ssb[wr * 32 + i * 16 + quad * 4 + r][wc] = ss[i][r];
    __syncthreads();
    if (tid < 64) {
        float s2 = ssb[tid][0] + ssb[tid][1];
        invn[rowbase + tid] = 1.f / fmaxf(sqrtf(s2), 1e-12f);
    }

    // t16 stores + tr LDS (transposed) writes
#pragma unroll
    for (int i = 0; i < 2; ++i)
#pragma unroll
        for (int ct = 0; ct < 4; ++ct)
#pragma unroll
            for (int r = 0; r < 4; ++r) {
                const int pl = wr * 32 + i * 16 + quad * 4 + r;
                const int c = wc * 64 + ct * 16 + l16;
                ushort bits = bf16bits(acc[i][ct][r]);
                t16[(size_t)(rowbase + pl) * kH + c] = bits;
                tr[c * 72 + pl] = bits;
            }
    __syncthreads();

    // coalesced tT writeout: 128 c-rows x 64 q
    ushort* tTb = tT16 + (size_t)b * kH * kN;
#pragma unroll
    for (int it = 0; it < 4; ++it) {
        int idx = tid + 256 * it;           // 0..1023
        int c = idx >> 3, ch = idx & 7;
        bf16x8 v = *(const bf16x8*)&tr[c * 72 + ch * 8];
        *(bf16x8*)&tTb[(size_t)c * kN + q0 + ch * 8] = v;
    }
}

// ---------------- fused MFMA aggregation (LDS-staged) ----------------
// 1024 thr = 16 waves (4 wp x 4 wq); P-tile 64, q-tile 64.
// All fragments from LDS; ew scattered-by-quad (4 lines/instr) prefetched.
__global__ __launch_bounds__(1024, 4) void agg_kernel(
    const ushort* __restrict__ t, const ushort* __restrict__ tT,
    const float* __restrict__ invn, const float* __restrict__ ew,
    ushort* __restrict__ hout, float* __restrict__ fout, int last)
{
    __shared__ ushort TQ[64 * 136];   // [q][d]  272B stride -> 2-way (free)
    __shared__ ushort TT[128 * 72];   // [c][q]  144B stride -> 2-way
    __shared__ ushort Spm[64 * 72];   // [p][q]  144B stride -> 2-way
    __shared__ float invPs[64];

    const int b = blockIdx.y, pbase = blockIdx.x * 64;
    const int tid = threadIdx.x, lane = tid & 63, wid = tid >> 6;
    const int wp = wid >> 2, wq = wid & 3, quad = lane >> 4, l16 = lane & 15;

    const ushort* tb  = t  + (size_t)b * kN * kH;
    const ushort* tTb = tT + (size_t)b * kH * kN;
    const float*  ewb = ew + (size_t)b * kN * kN;
    const float*  invb = invn + b * kN;

    if (tid < 64) invPs[tid] = invb[pbase + tid];

    // A-frags for this wave's 16 P-rows (held all kernel; 8 scattered loads, one-time)
    bf16x8 Af[4];
#pragma unroll
    for (int k = 0; k < 4; ++k)
        Af[k] = *(const bf16x8*)&tb[(size_t)(pbase + wp * 16 + l16) * kH + k * 32 + quad * 8];

    // staging thread map (coalesced): tQ 64x128 (16 thr/row), tT 128x64 (8 thr/row)
    const int sqRow = tid >> 4, sqCh = tid & 15;
    const int stRow = tid >> 3, stCh = tid & 7;
    bf16x8 rQ = *(const bf16x8*)&tb[(size_t)sqRow * kH + sqCh * 8];
    bf16x8 rT = *(const bf16x8*)&tTb[(size_t)stRow * kN + stCh * 8];

    const int ewRow = pbase + wp * 16 + quad * 4;
    float ewc[4], invQc;
    {
        const int qc = wq * 16 + l16;
        invQc = invb[qc];
#pragma unroll
        for (int r = 0; r < 4; ++r) ewc[r] = ewb[(size_t)(ewRow + r) * kN + qc];
    }

    __syncthreads();  // invPs visible
    float invPr[4];
#pragma unroll
    for (int r = 0; r < 4; ++r) invPr[r] = invPs[wp * 16 + quad * 4 + r];

    f32x4 oacc[2] = {(f32x4){0,0,0,0}, (f32x4){0,0,0,0}};

    for (int qt = 0; qt < kN / 64; ++qt) {
        // [A] publish staged tile
        *(bf16x8*)&TQ[sqRow * 136 + sqCh * 8] = rQ;
        *(bf16x8*)&TT[stRow * 72 + stCh * 8]  = rT;
        __syncthreads();  // [B]

        // [C] prefetch next tile (globals in flight across S-phase)
        float ewn[4] = {0.f, 0.f, 0.f, 0.f};
        float invQn = 0.f;
        if (qt + 1 < kN / 64) {
            const int qb2 = (qt + 1) * 64;
            rQ = *(const bf16x8*)&tb[(size_t)(qb2 + sqRow) * kH + sqCh * 8];
            rT = *(const bf16x8*)&tTb[(size_t)stRow * kN + qb2 + stCh * 8];
            const int qc = qb2 + wq * 16 + l16;
            invQn = invb[qc];
#pragma unroll
            for (int r = 0; r < 4; ++r) ewn[r] = ewb[(size_t)(ewRow + r) * kN + qc];
        }

        // [D] S-phase: dacc = tP(16) . tQ(16)^T over d=128
        f32x4 dacc = (f32x4){0.f, 0.f, 0.f, 0.f};
#pragma unroll
        for (int k = 0; k < 4; ++k) {
            bf16x8 Bf = *(const bf16x8*)&TQ[(wq * 16 + l16) * 136 + k * 32 + quad * 8];
            dacc = __builtin_amdgcn_mfma_f32_16x16x32_bf16(Af[k], Bf, dacc, 0, 0, 0);
        }
        // S' = dacc * ew * invQ -> bf16 -> Spm  (C-layout: row p=quad*4+r, col q=l16)
#pragma unroll
        for (int r = 0; r < 4; ++r)
            Spm[(wp * 16 + quad * 4 + r) * 72 + wq * 16 + l16] = bf16bits(dacc[r] * ewc[r] * invQc);
        __syncthreads();  // [E] Spm visible

        // [F] O-phase: oacc += S'[16p x 64q] @ t[64q x 32c]
#pragma unroll
        for (int k = 0; k < 2; ++k) {
            bf16x8 Sa = *(const bf16x8*)&Spm[(wp * 16 + l16) * 72 + k * 32 + quad * 8];
#pragma unroll
            for (int ct = 0; ct < 2; ++ct) {
                bf16x8 Bb = *(const bf16x8*)&TT[(wq * 32 + ct * 16 + l16) * 72 + k * 32 + quad * 8];
                oacc[ct] = __builtin_amdgcn_mfma_f32_16x16x32_bf16(Sa, Bb, oacc[ct], 0, 0, 0);
            }
        }
        __syncthreads();  // [G] all reads done -> next tile may overwrite

#pragma unroll
        for (int r = 0; r < 4; ++r) ewc[r] = ewn[r];
        invQc = invQn;
    }

    // store: O * invP (+relu -> bf16 h, or fp32 final)
#pragma unroll
    for (int ct = 0; ct < 2; ++ct)
#pragma unroll
        for (int r = 0; r < 4; ++r) {
            const int p = pbase + wp * 16 + quad * 4 + r;
            const int c = wq * 32 + ct * 16 + l16;
            float v = oacc[ct][r] * invPr[r];
            if (!last) {
                hout[(size_t)b * kN * kH + (size_t)p * kH + c] = bf16bits(fmaxf(v, 0.f));
            } else {
                fout[(size_t)b * kN * kH + (size_t)p * kH + c] = v;
            }
        }
}

extern "C" void kernel_launch(void* const* d_in, const int* in_sizes, int n_in,
                              void* d_out, int out_size, void* d_ws, size_t ws_size,
                              hipStream_t stream) {
    const float* x  = (const float*)d_in[0];
    const float* ew = (const float*)d_in[1];
    const float* W0 = (const float*)d_in[2];
    const float* b0 = (const float*)d_in[3];
    const float* W1 = (const float*)d_in[4];
    const float* b1 = (const float*)d_in[5];
    const float* W2 = (const float*)d_in[6];
    const float* b2 = (const float*)d_in[7];
    const float* bias[3] = {b0, b1, b2};

    const size_t nBNH = (size_t)kB * kN * kH;  // 2M
    ushort* h16  = (ushort*)d_ws;               // [B,N,H] bf16 (x, then relu h)
    ushort* t16  = h16 + nBNH;                  // [B,N,H] bf16 post-linear
    ushort* tT16 = t16 + nBNH;                  // [B,H,N] bf16 transposed
    float*  invn = (float*)(tT16 + nBNH);       // [B,N]
    ushort* WT   = (ushort*)(invn + (size_t)kB * kN);  // 3 x [H,D] bf16
    float*  out  = (float*)d_out;

    cvt_bf16_kernel<<<(int)(nBNH / 4 + 255) / 256, 256, 0, stream>>>(x, h16, (int)(nBNH / 4));
    cvt_wT_kernel<<<dim3(64, 3), 256, 0, stream>>>(W0, W1, W2, WT);

    for (int layer = 0; layer < 3; ++layer) {
        linear_tr_kernel<<<kB * kN / 64, 256, 0, stream>>>(
            h16, WT + (size_t)layer * kH * kH, bias[layer], t16, tT16, invn);
        agg_kernel<<<dim3(kN / 64, kB), 1024, 0, stream>>>(
            t16, tT16, invn, ew, h16, out, layer == 2 ? 1 : 0);
    }
}